// Round 1
// baseline (1114.335 us; speedup 1.0000x reference)
//
#include <hip/hip_runtime.h>
#include <hip/hip_bf16.h>
#include <stdint.h>

typedef unsigned short u16;
typedef unsigned int u32;

#define NEG_SLOPE 0.2f

__device__ __forceinline__ float bf2f(u16 u) {
    return __uint_as_float(((u32)u) << 16);
}
__device__ __forceinline__ u16 f2bf(float f) {
    u32 x = __float_as_uint(f);
    u32 r = (x + 0x7fffu + ((x >> 16) & 1u)) >> 16;  // round-to-nearest-even
    return (u16)r;
}

// ---------------- CSR build ----------------

__global__ void init_deg_kernel(int* deg, int N) {
    int i = blockIdx.x * blockDim.x + threadIdx.x;
    if (i < N) deg[i] = 1;  // self loop
}

__global__ void hist_kernel(const int* __restrict__ dst, int* deg, int E) {
    int e = blockIdx.x * blockDim.x + threadIdx.x;
    if (e < E) atomicAdd(&deg[dst[e]], 1);
}

__global__ void scan_kernel(const int* __restrict__ deg, int* offsets, int* cursor, int N) {
    __shared__ int s[1024];
    int t = threadIdx.x;
    int chunk = (N + 1023) / 1024;
    int beg = t * chunk;
    int end = beg + chunk; if (end > N) end = N; if (beg > N) beg = N;
    int sum = 0;
    for (int i = beg; i < end; i++) sum += deg[i];
    s[t] = sum;
    __syncthreads();
    for (int off = 1; off < 1024; off <<= 1) {
        int v = (t >= off) ? s[t - off] : 0;
        __syncthreads();
        s[t] += v;
        __syncthreads();
    }
    int run = s[t] - sum;  // exclusive prefix
    for (int i = beg; i < end; i++) {
        offsets[i] = run;
        cursor[i] = run;
        run += deg[i];
    }
    if (t == 1023) offsets[N] = s[1023];
}

__global__ void scatter_kernel(const int* __restrict__ src, const int* __restrict__ dst,
                               int* cursor, int* esrc, int E, int N) {
    int e = blockIdx.x * blockDim.x + threadIdx.x;
    if (e < E) {
        int d = dst[e];
        int idx = atomicAdd(&cursor[d], 1);
        esrc[idx] = src[e];
    } else if (e < E + N) {
        int i = e - E;
        int idx = atomicAdd(&cursor[i], 1);
        esrc[idx] = i;
    }
}

// ---------------- generic 64x64-tile SGEMM ----------------
// C[M, Nreal] = A[M, K] @ B[K, Nreal]; A fp32 or bf16, C fp32 or bf16.
// K must be a multiple of 32. Column tile = blockIdx.y*64.

template <bool ABF16, bool CBF16, bool BGUARD>
__global__ __launch_bounds__(256) void sgemm_tile(const void* __restrict__ Av,
                                                  const float* __restrict__ B,
                                                  void* __restrict__ Cv,
                                                  int M, int K, int Nreal) {
    __shared__ float As[32][68];
    __shared__ float Bs[32][64];
    const int tid = threadIdx.x;
    const int r0 = blockIdx.x * 64;
    const int c0 = blockIdx.y * 64;
    const int tx = tid & 15, ty = tid >> 4;
    float acc[4][4] = {};

    for (int kc = 0; kc < K; kc += 32) {
        // ---- stage A (transposed into As[k][row]) ----
        if (ABF16) {
            const u16* A = (const u16*)Av;
            int row = tid >> 2;
            int k8 = (tid & 3) * 8;
            int gr = r0 + row;
            uint4 v = make_uint4(0u, 0u, 0u, 0u);
            if (gr < M) v = *(const uint4*)(A + (size_t)gr * K + kc + k8);
            const u16* p = (const u16*)&v;
#pragma unroll
            for (int q = 0; q < 8; q++) As[k8 + q][row] = bf2f(p[q]);
        } else {
            const float* A = (const float*)Av;
#pragma unroll
            for (int i = 0; i < 2; i++) {
                int idx = tid + i * 256;
                int row = idx >> 3;
                int kq = (idx & 7) * 4;
                int gr = r0 + row;
                float4 v = make_float4(0.f, 0.f, 0.f, 0.f);
                if (gr < M) v = *(const float4*)(A + (size_t)gr * K + kc + kq);
                As[kq + 0][row] = v.x;
                As[kq + 1][row] = v.y;
                As[kq + 2][row] = v.z;
                As[kq + 3][row] = v.w;
            }
        }
        // ---- stage B ----
#pragma unroll
        for (int i = 0; i < 2; i++) {
            int idx = tid + i * 256;
            int br = idx >> 4;
            int bc = (idx & 15) * 4;
            const float* bp = B + (size_t)(kc + br) * Nreal + c0 + bc;
            if (BGUARD) {
#pragma unroll
                for (int q = 0; q < 4; q++)
                    Bs[br][bc + q] = (c0 + bc + q < Nreal) ? bp[q] : 0.f;
            } else {
                float4 v = *(const float4*)bp;
                Bs[br][bc + 0] = v.x;
                Bs[br][bc + 1] = v.y;
                Bs[br][bc + 2] = v.z;
                Bs[br][bc + 3] = v.w;
            }
        }
        __syncthreads();
#pragma unroll
        for (int k = 0; k < 32; k++) {
            float4 a = *(const float4*)&As[k][ty * 4];
            float4 b = *(const float4*)&Bs[k][tx * 4];
            float av[4] = {a.x, a.y, a.z, a.w};
            float bv[4] = {b.x, b.y, b.z, b.w};
#pragma unroll
            for (int i = 0; i < 4; i++)
#pragma unroll
                for (int j = 0; j < 4; j++) acc[i][j] = fmaf(av[i], bv[j], acc[i][j]);
        }
        __syncthreads();
    }
    // ---- epilogue ----
#pragma unroll
    for (int i = 0; i < 4; i++) {
        int gr = r0 + ty * 4 + i;
        if (gr >= M) continue;
#pragma unroll
        for (int j = 0; j < 4; j++) {
            int gc = c0 + tx * 4 + j;
            if (BGUARD && gc >= Nreal) continue;
            if (CBF16)
                ((u16*)Cv)[(size_t)gr * Nreal + gc] = f2bf(acc[i][j]);
            else
                ((float*)Cv)[(size_t)gr * Nreal + gc] = acc[i][j];
        }
    }
}

// ---------------- layer-1 attention ----------------

__global__ void logits1_kernel(const u16* __restrict__ h, const float* __restrict__ a_src,
                               const float* __restrict__ a_dst, float* als, float* ald, int N) {
    int t = blockIdx.x * blockDim.x + threadIdx.x;
    if (t >= N * 8) return;
    int n = t >> 3, hd = t & 7;
    const u16* row = h + (size_t)n * 512 + hd * 64;
    float s = 0.f, d = 0.f;
#pragma unroll
    for (int i = 0; i < 8; i++) {
        uint4 v = *(const uint4*)(row + i * 8);
        const u16* p = (const u16*)&v;
#pragma unroll
        for (int q = 0; q < 8; q++) {
            float x = bf2f(p[q]);
            s = fmaf(x, a_src[hd * 64 + i * 8 + q], s);
            d = fmaf(x, a_dst[hd * 64 + i * 8 + q], d);
        }
    }
    als[t] = s;
    ald[t] = d;
}

__global__ void att1_kernel(const int* __restrict__ offsets, const int* __restrict__ esrc,
                            const float* __restrict__ als, const float* __restrict__ ald,
                            float* ex, float* zinv, int N) {
    int t = blockIdx.x * blockDim.x + threadIdx.x;
    if (t >= N * 8) return;
    int n = t >> 3, hd = t & 7;
    int b = offsets[n], e = offsets[n + 1];
    float ad = ald[t];
    float z = 0.f;
    for (int j = b; j < e; j++) {
        int s = esrc[j];
        float v = als[s * 8 + hd] + ad;
        v = v > 0.f ? v : NEG_SLOPE * v;
        float ev = __expf(v);
        ex[(size_t)j * 8 + hd] = ev;
        z += ev;
    }
    zinv[t] = 1.f / z;  // z > 0 guaranteed (self loop)
}

__global__ void agg1_kernel(const int* __restrict__ offsets, const int* __restrict__ esrc,
                            const u16* __restrict__ h, const float* __restrict__ ex,
                            const float* __restrict__ zinv, const float* __restrict__ b1,
                            u16* h2, int N) {
    int t = blockIdx.x * blockDim.x + threadIdx.x;
    if (t >= N * 512) return;
    int n = t >> 9, r = t & 511, hd = r >> 6;
    int b = offsets[n], e = offsets[n + 1];
    float acc = 0.f;
    for (int j = b; j < e; j++) {
        int s = esrc[j];
        float w = ex[(size_t)j * 8 + hd];
        acc = fmaf(w, bf2f(h[(size_t)s * 512 + r]), acc);
    }
    float val = acc * zinv[n * 8 + hd] + b1[r];
    val = val > 0.f ? val : 0.f;  // ReLU between layers
    h2[t] = f2bf(val);
}

// ---------------- layer-2 attention ----------------

__global__ void logits2_kernel(const float* __restrict__ g, const float* __restrict__ a_src,
                               const float* __restrict__ a_dst, float* als, float* ald, int N) {
    int n = blockIdx.x * blockDim.x + threadIdx.x;
    if (n >= N) return;
    const float* row = g + (size_t)n * 40;
    float s = 0.f, d = 0.f;
#pragma unroll
    for (int i = 0; i < 10; i++) {
        float4 v = *(const float4*)(row + i * 4);
        float vv[4] = {v.x, v.y, v.z, v.w};
#pragma unroll
        for (int q = 0; q < 4; q++) {
            s = fmaf(vv[q], a_src[i * 4 + q], s);
            d = fmaf(vv[q], a_dst[i * 4 + q], d);
        }
    }
    als[n] = s;
    ald[n] = d;
}

__global__ void att2_kernel(const int* __restrict__ offsets, const int* __restrict__ esrc,
                            const float* __restrict__ als, const float* __restrict__ ald,
                            float* ex, float* zinv, int N) {
    int n = blockIdx.x * blockDim.x + threadIdx.x;
    if (n >= N) return;
    int b = offsets[n], e = offsets[n + 1];
    float ad = ald[n];
    float z = 0.f;
    for (int j = b; j < e; j++) {
        int s = esrc[j];
        float v = als[s] + ad;
        v = v > 0.f ? v : NEG_SLOPE * v;
        float ev = __expf(v);
        ex[j] = ev;
        z += ev;
    }
    zinv[n] = 1.f / z;
}

__global__ void agg2_kernel(const int* __restrict__ offsets, const int* __restrict__ esrc,
                            const float* __restrict__ g, const float* __restrict__ ex,
                            const float* __restrict__ zinv, const float* __restrict__ b2,
                            float* out, int N) {
    int t = blockIdx.x * blockDim.x + threadIdx.x;
    if (t >= N * 64) return;
    int n = t >> 6, c = t & 63;
    if (c >= 40) return;
    int b = offsets[n], e = offsets[n + 1];
    float acc = 0.f;
    for (int j = b; j < e; j++) {
        int s = esrc[j];
        acc = fmaf(ex[j], g[(size_t)s * 40 + c], acc);
    }
    out[(size_t)n * 40 + c] = acc * zinv[n] + b2[c];
}

// ---------------- host launch ----------------

extern "C" void kernel_launch(void* const* d_in, const int* in_sizes, int n_in,
                              void* d_out, int out_size, void* d_ws, size_t ws_size,
                              hipStream_t stream) {
    const float* x   = (const float*)d_in[0];
    const int*   ei  = (const int*)d_in[1];
    const float* W1  = (const float*)d_in[2];
    const float* a1s = (const float*)d_in[3];
    const float* a1d = (const float*)d_in[4];
    const float* b1  = (const float*)d_in[5];
    const float* W2  = (const float*)d_in[6];
    const float* a2s = (const float*)d_in[7];
    const float* a2d = (const float*)d_in[8];
    const float* b2  = (const float*)d_in[9];
    float* out = (float*)d_out;

    const int F = 128;
    const int N = in_sizes[0] / F;
    const int E = in_sizes[1] / 2;
    const int ET = E + N;  // edges + self loops

    char* ws = (char*)d_ws;
    size_t off = 0;
    auto alloc = [&](size_t bytes) -> char* {
        char* p = ws + off;
        off += (bytes + 255) & ~(size_t)255;
        return p;
    };
    u16*   h     = (u16*)alloc((size_t)N * 512 * 2);
    u16*   h2    = (u16*)alloc((size_t)N * 512 * 2);
    float* ex1   = (float*)alloc((size_t)ET * 8 * 4);
    int*   esrc  = (int*)alloc((size_t)ET * 4);
    float* als1  = (float*)alloc((size_t)N * 8 * 4);
    float* ald1  = (float*)alloc((size_t)N * 8 * 4);
    float* zinv1 = (float*)alloc((size_t)N * 8 * 4);
    int*   deg   = (int*)alloc((size_t)N * 4);
    int*   offs  = (int*)alloc((size_t)(N + 1) * 4);
    int*   curs  = (int*)alloc((size_t)N * 4);

    // layer-2 buffers alias the h region (h is dead after agg1)
    char* l2 = (char*)h;
    size_t o2 = 0;
    auto alloc2 = [&](size_t bytes) -> char* {
        char* p = l2 + o2;
        o2 += (bytes + 255) & ~(size_t)255;
        return p;
    };
    float* g     = (float*)alloc2((size_t)N * 40 * 4);
    float* als2  = (float*)alloc2((size_t)N * 4);
    float* ald2  = (float*)alloc2((size_t)N * 4);
    float* zinv2 = (float*)alloc2((size_t)N * 4);
    float* ex2   = (float*)alloc2((size_t)ET * 4);

    const int TPB = 256;
    const int* e_src = ei;      // edge_index[0]
    const int* e_dst = ei + E;  // edge_index[1]

    // CSR build
    init_deg_kernel<<<(N + TPB - 1) / TPB, TPB, 0, stream>>>(deg, N);
    hist_kernel<<<(E + TPB - 1) / TPB, TPB, 0, stream>>>(e_dst, deg, E);
    scan_kernel<<<1, 1024, 0, stream>>>(deg, offs, curs, N);
    scatter_kernel<<<(ET + TPB - 1) / TPB, TPB, 0, stream>>>(e_src, e_dst, curs, esrc, E, N);

    // layer 1
    sgemm_tile<false, true, false><<<dim3((N + 63) / 64, 8), 256, 0, stream>>>(
        x, W1, h, N, 128, 512);
    logits1_kernel<<<(N * 8 + TPB - 1) / TPB, TPB, 0, stream>>>(h, a1s, a1d, als1, ald1, N);
    att1_kernel<<<(N * 8 + TPB - 1) / TPB, TPB, 0, stream>>>(offs, esrc, als1, ald1, ex1, zinv1, N);
    agg1_kernel<<<((size_t)N * 512 + TPB - 1) / TPB, TPB, 0, stream>>>(
        offs, esrc, h, ex1, zinv1, b1, h2, N);

    // layer 2
    sgemm_tile<true, false, true><<<dim3((N + 63) / 64, 1), 256, 0, stream>>>(
        h2, W2, g, N, 512, 40);
    logits2_kernel<<<(N + TPB - 1) / TPB, TPB, 0, stream>>>(g, a2s, a2d, als2, ald2, N);
    att2_kernel<<<(N + TPB - 1) / TPB, TPB, 0, stream>>>(offs, esrc, als2, ald2, ex2, zinv2, N);
    agg2_kernel<<<((size_t)N * 64 + TPB - 1) / TPB, TPB, 0, stream>>>(
        offs, esrc, g, ex2, zinv2, b2, out, N);
}

// Round 2
// 704.080 us; speedup vs baseline: 1.5827x; 1.5827x over previous
//
#include <hip/hip_runtime.h>
#include <hip/hip_bf16.h>
#include <stdint.h>

typedef unsigned short u16;
typedef unsigned int u32;

#define NEG_SLOPE 0.2f

__device__ __forceinline__ float bf2f(u16 u) {
    return __uint_as_float(((u32)u) << 16);
}
__device__ __forceinline__ u16 f2bf(float f) {
    u32 x = __float_as_uint(f);
    u32 r = (x + 0x7fffu + ((x >> 16) & 1u)) >> 16;  // round-to-nearest-even
    return (u16)r;
}

// ---------------- CSR build ----------------

__global__ void init_deg_kernel(int* deg, int N) {
    int i = blockIdx.x * blockDim.x + threadIdx.x;
    if (i < N) deg[i] = 1;  // self loop
}

__global__ void hist_kernel(const int* __restrict__ dst, int* deg, int E) {
    int e = blockIdx.x * blockDim.x + threadIdx.x;
    if (e < E) atomicAdd(&deg[dst[e]], 1);
}

__global__ void scan_kernel(const int* __restrict__ deg, int* offsets, int* cursor, int N) {
    __shared__ int s[1024];
    int t = threadIdx.x;
    int chunk = (N + 1023) / 1024;
    int beg = t * chunk;
    int end = beg + chunk; if (end > N) end = N; if (beg > N) beg = N;
    int sum = 0;
    for (int i = beg; i < end; i++) sum += deg[i];
    s[t] = sum;
    __syncthreads();
    for (int off = 1; off < 1024; off <<= 1) {
        int v = (t >= off) ? s[t - off] : 0;
        __syncthreads();
        s[t] += v;
        __syncthreads();
    }
    int run = s[t] - sum;  // exclusive prefix
    for (int i = beg; i < end; i++) {
        offsets[i] = run;
        cursor[i] = run;
        run += deg[i];
    }
    if (t == 1023) offsets[N] = s[1023];
}

__global__ void scatter_kernel(const int* __restrict__ src, const int* __restrict__ dst,
                               int* cursor, int* esrc, int E, int N) {
    int e = blockIdx.x * blockDim.x + threadIdx.x;
    if (e < E) {
        int d = dst[e];
        int idx = atomicAdd(&cursor[d], 1);
        esrc[idx] = src[e];
    } else if (e < E + N) {
        int i = e - E;
        int idx = atomicAdd(&cursor[i], 1);
        esrc[idx] = i;
    }
}

// ---------------- generic 64x64-tile SGEMM ----------------

template <bool ABF16, bool CBF16, bool BGUARD>
__global__ __launch_bounds__(256) void sgemm_tile(const void* __restrict__ Av,
                                                  const float* __restrict__ B,
                                                  void* __restrict__ Cv,
                                                  int M, int K, int Nreal) {
    __shared__ float As[32][68];
    __shared__ float Bs[32][64];
    const int tid = threadIdx.x;
    const int r0 = blockIdx.x * 64;
    const int c0 = blockIdx.y * 64;
    const int tx = tid & 15, ty = tid >> 4;
    float acc[4][4] = {};

    for (int kc = 0; kc < K; kc += 32) {
        if (ABF16) {
            const u16* A = (const u16*)Av;
            int row = tid >> 2;
            int k8 = (tid & 3) * 8;
            int gr = r0 + row;
            uint4 v = make_uint4(0u, 0u, 0u, 0u);
            if (gr < M) v = *(const uint4*)(A + (size_t)gr * K + kc + k8);
            const u16* p = (const u16*)&v;
#pragma unroll
            for (int q = 0; q < 8; q++) As[k8 + q][row] = bf2f(p[q]);
        } else {
            const float* A = (const float*)Av;
#pragma unroll
            for (int i = 0; i < 2; i++) {
                int idx = tid + i * 256;
                int row = idx >> 3;
                int kq = (idx & 7) * 4;
                int gr = r0 + row;
                float4 v = make_float4(0.f, 0.f, 0.f, 0.f);
                if (gr < M) v = *(const float4*)(A + (size_t)gr * K + kc + kq);
                As[kq + 0][row] = v.x;
                As[kq + 1][row] = v.y;
                As[kq + 2][row] = v.z;
                As[kq + 3][row] = v.w;
            }
        }
#pragma unroll
        for (int i = 0; i < 2; i++) {
            int idx = tid + i * 256;
            int br = idx >> 4;
            int bc = (idx & 15) * 4;
            const float* bp = B + (size_t)(kc + br) * Nreal + c0 + bc;
            if (BGUARD) {
#pragma unroll
                for (int q = 0; q < 4; q++)
                    Bs[br][bc + q] = (c0 + bc + q < Nreal) ? bp[q] : 0.f;
            } else {
                float4 v = *(const float4*)bp;
                Bs[br][bc + 0] = v.x;
                Bs[br][bc + 1] = v.y;
                Bs[br][bc + 2] = v.z;
                Bs[br][bc + 3] = v.w;
            }
        }
        __syncthreads();
#pragma unroll
        for (int k = 0; k < 32; k++) {
            float4 a = *(const float4*)&As[k][ty * 4];
            float4 b = *(const float4*)&Bs[k][tx * 4];
            float av[4] = {a.x, a.y, a.z, a.w};
            float bv[4] = {b.x, b.y, b.z, b.w};
#pragma unroll
            for (int i = 0; i < 4; i++)
#pragma unroll
                for (int j = 0; j < 4; j++) acc[i][j] = fmaf(av[i], bv[j], acc[i][j]);
        }
        __syncthreads();
    }
#pragma unroll
    for (int i = 0; i < 4; i++) {
        int gr = r0 + ty * 4 + i;
        if (gr >= M) continue;
#pragma unroll
        for (int j = 0; j < 4; j++) {
            int gc = c0 + tx * 4 + j;
            if (BGUARD && gc >= Nreal) continue;
            if (CBF16)
                ((u16*)Cv)[(size_t)gr * Nreal + gc] = f2bf(acc[i][j]);
            else
                ((float*)Cv)[(size_t)gr * Nreal + gc] = acc[i][j];
        }
    }
}

// ---------------- layer-1 attention ----------------

__global__ void logits1_kernel(const u16* __restrict__ h, const float* __restrict__ a_src,
                               const float* __restrict__ a_dst, float* als, float* ald, int N) {
    int t = blockIdx.x * blockDim.x + threadIdx.x;
    if (t >= N * 8) return;
    int n = t >> 3, hd = t & 7;
    const u16* row = h + (size_t)n * 512 + hd * 64;
    float s = 0.f, d = 0.f;
#pragma unroll
    for (int i = 0; i < 8; i++) {
        uint4 v = *(const uint4*)(row + i * 8);
        const u16* p = (const u16*)&v;
#pragma unroll
        for (int q = 0; q < 8; q++) {
            float x = bf2f(p[q]);
            s = fmaf(x, a_src[hd * 64 + i * 8 + q], s);
            d = fmaf(x, a_dst[hd * 64 + i * 8 + q], d);
        }
    }
    als[t] = s;
    ald[t] = d;
}

// Fused softmax + aggregation, layer 1.
// One wave per destination node; lane covers 8 channels (16B of bf16).
// Per edge: wave reads the full 1KB h row coalesced; exp / z-sum inline.
__global__ __launch_bounds__(256) void agg1_fused(
    const int* __restrict__ offs, const int* __restrict__ esrc,
    const u16* __restrict__ h, const float* __restrict__ als,
    const float* __restrict__ ald, const float* __restrict__ b1,
    u16* __restrict__ h2, int N) {
    int wid = blockIdx.x * 4 + (threadIdx.x >> 6);
    if (wid >= N) return;
    int lane = threadIdx.x & 63;
    int hd = lane >> 3;
    int b = offs[wid], e = offs[wid + 1];
    float ad = ald[wid * 8 + hd];
    float acc[8] = {};
    float zs = 0.f;
    const u16* hp = h + (size_t)lane * 8;
    for (int jb = b; jb < e; jb += 64) {
        int nk = min(64, e - jb);
        int my = (jb + lane < e) ? esrc[jb + lane] : 0;
        for (int k = 0; k < nk; k++) {
            int s = __shfl(my, k);
            float v = als[s * 8 + hd] + ad;
            v = v > 0.f ? v : NEG_SLOPE * v;
            float w = __expf(v);
            zs += w;  // same for all 8 lanes of this head -> z per head
            uint4 hv = *(const uint4*)(hp + (size_t)s * 512);
            const u16* p = (const u16*)&hv;
#pragma unroll
            for (int q = 0; q < 8; q++) acc[q] = fmaf(w, bf2f(p[q]), acc[q]);
        }
    }
    float zi = 1.f / zs;  // >0 guaranteed: self loop
#pragma unroll
    for (int q = 0; q < 8; q++) {
        float val = fmaf(acc[q], zi, b1[lane * 8 + q]);
        val = val > 0.f ? val : 0.f;  // inter-layer ReLU
        h2[(size_t)wid * 512 + lane * 8 + q] = f2bf(val);
    }
}

// ---------------- layer-2 attention ----------------

__global__ void logits2_kernel(const float* __restrict__ g, const float* __restrict__ a_src,
                               const float* __restrict__ a_dst, float* als, float* ald, int N) {
    int n = blockIdx.x * blockDim.x + threadIdx.x;
    if (n >= N) return;
    const float* row = g + (size_t)n * 40;
    float s = 0.f, d = 0.f;
#pragma unroll
    for (int i = 0; i < 10; i++) {
        float4 v = *(const float4*)(row + i * 4);
        float vv[4] = {v.x, v.y, v.z, v.w};
#pragma unroll
        for (int q = 0; q < 4; q++) {
            s = fmaf(vv[q], a_src[i * 4 + q], s);
            d = fmaf(vv[q], a_dst[i * 4 + q], d);
        }
    }
    als[n] = s;
    ald[n] = d;
}

// Fused softmax + aggregation, layer 2. One wave per node; lane = class (<40).
__global__ __launch_bounds__(256) void agg2_fused(
    const int* __restrict__ offs, const int* __restrict__ esrc,
    const float* __restrict__ g, const float* __restrict__ als,
    const float* __restrict__ ald, const float* __restrict__ b2,
    float* __restrict__ out, int N) {
    int wid = blockIdx.x * 4 + (threadIdx.x >> 6);
    if (wid >= N) return;
    int lane = threadIdx.x & 63;
    int b = offs[wid], e = offs[wid + 1];
    float ad = ald[wid];
    float acc = 0.f, zs = 0.f;
    bool active = lane < 40;
    for (int jb = b; jb < e; jb += 64) {
        int nk = min(64, e - jb);
        int my = (jb + lane < e) ? esrc[jb + lane] : 0;
        for (int k = 0; k < nk; k++) {
            int s = __shfl(my, k);
            float v = als[s] + ad;
            v = v > 0.f ? v : NEG_SLOPE * v;
            float w = __expf(v);
            zs += w;
            if (active) acc = fmaf(w, g[(size_t)s * 40 + lane], acc);
        }
    }
    if (active) out[(size_t)wid * 40 + lane] = acc / zs + b2[lane];
}

// ---------------- host launch ----------------

extern "C" void kernel_launch(void* const* d_in, const int* in_sizes, int n_in,
                              void* d_out, int out_size, void* d_ws, size_t ws_size,
                              hipStream_t stream) {
    const float* x   = (const float*)d_in[0];
    const int*   ei  = (const int*)d_in[1];
    const float* W1  = (const float*)d_in[2];
    const float* a1s = (const float*)d_in[3];
    const float* a1d = (const float*)d_in[4];
    const float* b1  = (const float*)d_in[5];
    const float* W2  = (const float*)d_in[6];
    const float* a2s = (const float*)d_in[7];
    const float* a2d = (const float*)d_in[8];
    const float* b2  = (const float*)d_in[9];
    float* out = (float*)d_out;

    const int F = 128;
    const int N = in_sizes[0] / F;
    const int E = in_sizes[1] / 2;
    const int ET = E + N;

    char* ws = (char*)d_ws;
    size_t off = 0;
    auto alloc = [&](size_t bytes) -> char* {
        char* p = ws + off;
        off += (bytes + 255) & ~(size_t)255;
        return p;
    };
    u16*   h     = (u16*)alloc((size_t)N * 512 * 2);
    u16*   h2    = (u16*)alloc((size_t)N * 512 * 2);
    int*   esrc  = (int*)alloc((size_t)ET * 4);
    float* als1  = (float*)alloc((size_t)N * 8 * 4);
    float* ald1  = (float*)alloc((size_t)N * 8 * 4);
    int*   deg   = (int*)alloc((size_t)N * 4);
    int*   offs  = (int*)alloc((size_t)(N + 1) * 4);
    int*   curs  = (int*)alloc((size_t)N * 4);

    // layer-2 buffers alias the h region (h is dead after agg1_fused)
    char* l2 = (char*)h;
    size_t o2 = 0;
    auto alloc2 = [&](size_t bytes) -> char* {
        char* p = l2 + o2;
        o2 += (bytes + 255) & ~(size_t)255;
        return p;
    };
    float* g    = (float*)alloc2((size_t)N * 40 * 4);
    float* als2 = (float*)alloc2((size_t)N * 4);
    float* ald2 = (float*)alloc2((size_t)N * 4);

    const int TPB = 256;
    const int* e_src = ei;
    const int* e_dst = ei + E;

    // CSR build
    init_deg_kernel<<<(N + TPB - 1) / TPB, TPB, 0, stream>>>(deg, N);
    hist_kernel<<<(E + TPB - 1) / TPB, TPB, 0, stream>>>(e_dst, deg, E);
    scan_kernel<<<1, 1024, 0, stream>>>(deg, offs, curs, N);
    scatter_kernel<<<(ET + TPB - 1) / TPB, TPB, 0, stream>>>(e_src, e_dst, curs, esrc, E, N);

    // layer 1
    sgemm_tile<false, true, false><<<dim3((N + 63) / 64, 8), 256, 0, stream>>>(
        x, W1, h, N, 128, 512);
    logits1_kernel<<<(N * 8 + TPB - 1) / TPB, TPB, 0, stream>>>(h, a1s, a1d, als1, ald1, N);
    agg1_fused<<<(N + 3) / 4, 256, 0, stream>>>(offs, esrc, h, als1, ald1, b1, h2, N);

    // layer 2
    sgemm_tile<true, false, true><<<dim3((N + 63) / 64, 1), 256, 0, stream>>>(
        h2, W2, g, N, 512, 40);
    logits2_kernel<<<(N + TPB - 1) / TPB, TPB, 0, stream>>>(g, a2s, a2d, als2, ald2, N);
    agg2_fused<<<(N + 3) / 4, 256, 0, stream>>>(offs, esrc, g, als2, ald2, b2, out, N);
}

// Round 3
// 587.634 us; speedup vs baseline: 1.8963x; 1.1982x over previous
//
#include <hip/hip_runtime.h>
#include <hip/hip_bf16.h>
#include <stdint.h>

typedef unsigned short u16;
typedef unsigned int u32;
typedef __attribute__((ext_vector_type(8))) __bf16 bf16x8;
typedef __attribute__((ext_vector_type(4))) float f32x4;

#define NEG_SLOPE 0.2f

__device__ __forceinline__ float bf2f(u16 u) {
    return __uint_as_float(((u32)u) << 16);
}
__device__ __forceinline__ u16 f2bf(float f) {
    u32 x = __float_as_uint(f);
    u32 r = (x + 0x7fffu + ((x >> 16) & 1u)) >> 16;  // round-to-nearest-even
    return (u16)r;
}

// ---------------- CSR build ----------------

__global__ void init_deg_kernel(int* deg, int N) {
    int i = blockIdx.x * blockDim.x + threadIdx.x;
    if (i < N) deg[i] = 1;  // self loop
}

__global__ void hist_kernel(const int* __restrict__ dst, int* deg, int E) {
    int e = blockIdx.x * blockDim.x + threadIdx.x;
    if (e < E) atomicAdd(&deg[dst[e]], 1);
}

__global__ void scan_kernel(const int* __restrict__ deg, int* offsets, int* cursor, int N) {
    __shared__ int s[1024];
    int t = threadIdx.x;
    int chunk = (N + 1023) / 1024;
    int beg = t * chunk;
    int end = beg + chunk; if (end > N) end = N; if (beg > N) beg = N;
    int sum = 0;
    for (int i = beg; i < end; i++) sum += deg[i];
    s[t] = sum;
    __syncthreads();
    for (int off = 1; off < 1024; off <<= 1) {
        int v = (t >= off) ? s[t - off] : 0;
        __syncthreads();
        s[t] += v;
        __syncthreads();
    }
    int run = s[t] - sum;  // exclusive prefix
    for (int i = beg; i < end; i++) {
        offsets[i] = run;
        cursor[i] = run;
        run += deg[i];
    }
    if (t == 1023) offsets[N] = s[1023];
}

__global__ void scatter_kernel(const int* __restrict__ src, const int* __restrict__ dst,
                               int* cursor, int* esrc, int E, int N) {
    int e = blockIdx.x * blockDim.x + threadIdx.x;
    if (e < E) {
        int d = dst[e];
        int idx = atomicAdd(&cursor[d], 1);
        esrc[idx] = src[e];
    } else if (e < E + N) {
        int i = e - E;
        int idx = atomicAdd(&cursor[i], 1);
        esrc[idx] = i;
    }
}

// ---------------- input prep (casts / transposes) ----------------

__global__ void cast_bf16_kernel(const float* __restrict__ in, u16* __restrict__ out, int n) {
    int base = (blockIdx.x * blockDim.x + threadIdx.x) * 4;
    if (base >= n) return;
    float4 v = *(const float4*)(in + base);  // n is a multiple of 4 here
    out[base + 0] = f2bf(v.x);
    out[base + 1] = f2bf(v.y);
    out[base + 2] = f2bf(v.z);
    out[base + 3] = f2bf(v.w);
}

// W1[128,512] -> w1t[512,128] bf16 (N x K)
__global__ void prep_w1t_kernel(const float* __restrict__ W1, u16* __restrict__ w1t) {
    int t = blockIdx.x * blockDim.x + threadIdx.x;  // t < 512*128
    int nn = t >> 7, k = t & 127;
    w1t[t] = f2bf(W1[k * 512 + nn]);
}

// W2[512,40] -> w2t[64,512] bf16 (N x K), rows 40..63 zero
__global__ void prep_w2t_kernel(const float* __restrict__ W2, u16* __restrict__ w2t) {
    int t = blockIdx.x * blockDim.x + threadIdx.x;  // t < 64*512
    int nn = t >> 9, k = t & 511;
    w2t[t] = (nn < 40) ? f2bf(W2[k * 40 + nn]) : (u16)0;
}

// ---------------- bf16 MFMA GEMM ----------------
// C[M, ldc] = A[M, K](bf16) @ Bt[Ncols, K](bf16)^T, store cols < Nstore.
// Block tile 128 x BN, 4 waves of 64 x (BN/2). LDS rows padded to 40 bf16
// (80 B) so 16-lane frag reads are 2-way bank-aliased (free per m136).

template <int BN, bool CBF16>
__global__ __launch_bounds__(256) void mfma_gemm(
    const u16* __restrict__ A, const u16* __restrict__ Bt, void* __restrict__ Cv,
    int M, int K, int Nstore, int ldc) {
    constexpr int LDT = 40;
    constexpr int NI = BN / 32;  // n-tiles per wave
    __shared__ u16 As[128 * LDT];
    __shared__ u16 Bs[BN * LDT];
    const int tid = threadIdx.x;
    const int r0 = blockIdx.x * 128;
    const int c0 = blockIdx.y * BN;
    const int lane = tid & 63, w = tid >> 6;
    const int quad = lane >> 4, l16 = lane & 15;
    const int wm = (w >> 1) * 64;
    const int wn = (w & 1) * (BN / 2);
    f32x4 acc[4][NI] = {};

    for (int kc = 0; kc < K; kc += 32) {
        // stage A: 128 rows x 32 bf16 (each thread 32B)
        {
            int row = tid >> 1, half = tid & 1;
            int gr = r0 + row;
            uint4 v0 = make_uint4(0u, 0u, 0u, 0u), v1 = v0;
            if (gr < M) {
                const u16* p = A + (size_t)gr * K + kc + half * 16;
                v0 = *(const uint4*)p;
                v1 = *(const uint4*)(p + 8);
            }
            *(uint4*)&As[row * LDT + half * 16] = v0;
            *(uint4*)&As[row * LDT + half * 16 + 8] = v1;
        }
        // stage B: BN rows x 32 bf16
        if (BN == 128) {
            int row = tid >> 1, half = tid & 1;
            const u16* p = Bt + (size_t)(c0 + row) * K + kc + half * 16;
            uint4 v0 = *(const uint4*)p;
            uint4 v1 = *(const uint4*)(p + 8);
            *(uint4*)&Bs[row * LDT + half * 16] = v0;
            *(uint4*)&Bs[row * LDT + half * 16 + 8] = v1;
        } else {  // BN == 64: each thread 16B
            int row = tid >> 2, qo = (tid & 3) * 8;
            uint4 v = *(const uint4*)(Bt + (size_t)(c0 + row) * K + kc + qo);
            *(uint4*)&Bs[row * LDT + qo] = v;
        }
        __syncthreads();

        bf16x8 af[4], bfr[NI];
#pragma unroll
        for (int mi = 0; mi < 4; mi++) {
            uint4 v = *(const uint4*)&As[(wm + mi * 16 + l16) * LDT + quad * 8];
            af[mi] = __builtin_bit_cast(bf16x8, v);
        }
#pragma unroll
        for (int ni = 0; ni < NI; ni++) {
            uint4 v = *(const uint4*)&Bs[(wn + ni * 16 + l16) * LDT + quad * 8];
            bfr[ni] = __builtin_bit_cast(bf16x8, v);
        }
#pragma unroll
        for (int mi = 0; mi < 4; mi++)
#pragma unroll
            for (int ni = 0; ni < NI; ni++)
                acc[mi][ni] = __builtin_amdgcn_mfma_f32_16x16x32_bf16(
                    af[mi], bfr[ni], acc[mi][ni], 0, 0, 0);
        __syncthreads();
    }
    // epilogue: D row = quad*4 + reg, col = l16 (verified m89/m91 mapping)
#pragma unroll
    for (int mi = 0; mi < 4; mi++) {
#pragma unroll
        for (int r = 0; r < 4; r++) {
            int gr = r0 + wm + mi * 16 + quad * 4 + r;
            if (gr >= M) continue;
#pragma unroll
            for (int ni = 0; ni < NI; ni++) {
                int gc = c0 + wn + ni * 16 + l16;
                if (gc >= Nstore) continue;
                if (CBF16)
                    ((u16*)Cv)[(size_t)gr * ldc + gc] = f2bf(acc[mi][ni][r]);
                else
                    ((float*)Cv)[(size_t)gr * ldc + gc] = acc[mi][ni][r];
            }
        }
    }
}

// ---------------- layer-1 attention ----------------

__global__ void logits1_kernel(const u16* __restrict__ h, const float* __restrict__ a_src,
                               const float* __restrict__ a_dst, float* als, float* ald, int N) {
    int t = blockIdx.x * blockDim.x + threadIdx.x;
    if (t >= N * 8) return;
    int n = t >> 3, hd = t & 7;
    const u16* row = h + (size_t)n * 512 + hd * 64;
    float s = 0.f, d = 0.f;
#pragma unroll
    for (int i = 0; i < 8; i++) {
        uint4 v = *(const uint4*)(row + i * 8);
        const u16* p = (const u16*)&v;
#pragma unroll
        for (int q = 0; q < 8; q++) {
            float x = bf2f(p[q]);
            s = fmaf(x, a_src[hd * 64 + i * 8 + q], s);
            d = fmaf(x, a_dst[hd * 64 + i * 8 + q], d);
        }
    }
    als[t] = s;
    ald[t] = d;
}

// Fused softmax + aggregation, layer 1. One wave per destination node;
// lane covers 8 channels (16B of bf16) => full 1KB h row per edge, coalesced.
__global__ __launch_bounds__(256) void agg1_fused(
    const int* __restrict__ offs, const int* __restrict__ esrc,
    const u16* __restrict__ h, const float* __restrict__ als,
    const float* __restrict__ ald, const float* __restrict__ b1,
    u16* __restrict__ h2, int N) {
    int wid = blockIdx.x * 4 + (threadIdx.x >> 6);
    if (wid >= N) return;
    int lane = threadIdx.x & 63;
    int hd = lane >> 3;
    int b = offs[wid], e = offs[wid + 1];
    float ad = ald[wid * 8 + hd];
    float acc[8] = {};
    float zs = 0.f;
    const u16* hp = h + (size_t)lane * 8;
    for (int jb = b; jb < e; jb += 64) {
        int nk = min(64, e - jb);
        int my = (jb + lane < e) ? esrc[jb + lane] : 0;
        for (int k = 0; k < nk; k++) {
            int s = __shfl(my, k);
            float v = als[s * 8 + hd] + ad;
            v = v > 0.f ? v : NEG_SLOPE * v;
            float w = __expf(v);
            zs += w;
            uint4 hv = *(const uint4*)(hp + (size_t)s * 512);
            const u16* p = (const u16*)&hv;
#pragma unroll
            for (int q = 0; q < 8; q++) acc[q] = fmaf(w, bf2f(p[q]), acc[q]);
        }
    }
    float zi = 1.f / zs;
#pragma unroll
    for (int q = 0; q < 8; q++) {
        float val = fmaf(acc[q], zi, b1[lane * 8 + q]);
        val = val > 0.f ? val : 0.f;  // inter-layer ReLU
        h2[(size_t)wid * 512 + lane * 8 + q] = f2bf(val);
    }
}

// ---------------- layer-2 attention ----------------

__global__ void logits2_kernel(const float* __restrict__ g, const float* __restrict__ a_src,
                               const float* __restrict__ a_dst, float* als, float* ald, int N) {
    int n = blockIdx.x * blockDim.x + threadIdx.x;
    if (n >= N) return;
    const float* row = g + (size_t)n * 40;
    float s = 0.f, d = 0.f;
#pragma unroll
    for (int i = 0; i < 10; i++) {
        float4 v = *(const float4*)(row + i * 4);
        float vv[4] = {v.x, v.y, v.z, v.w};
#pragma unroll
        for (int q = 0; q < 4; q++) {
            s = fmaf(vv[q], a_src[i * 4 + q], s);
            d = fmaf(vv[q], a_dst[i * 4 + q], d);
        }
    }
    als[n] = s;
    ald[n] = d;
}

__global__ __launch_bounds__(256) void agg2_fused(
    const int* __restrict__ offs, const int* __restrict__ esrc,
    const float* __restrict__ g, const float* __restrict__ als,
    const float* __restrict__ ald, const float* __restrict__ b2,
    float* __restrict__ out, int N) {
    int wid = blockIdx.x * 4 + (threadIdx.x >> 6);
    if (wid >= N) return;
    int lane = threadIdx.x & 63;
    int b = offs[wid], e = offs[wid + 1];
    float ad = ald[wid];
    float acc = 0.f, zs = 0.f;
    bool active = lane < 40;
    for (int jb = b; jb < e; jb += 64) {
        int nk = min(64, e - jb);
        int my = (jb + lane < e) ? esrc[jb + lane] : 0;
        for (int k = 0; k < nk; k++) {
            int s = __shfl(my, k);
            float v = als[s] + ad;
            v = v > 0.f ? v : NEG_SLOPE * v;
            float w = __expf(v);
            zs += w;
            if (active) acc = fmaf(w, g[(size_t)s * 40 + lane], acc);
        }
    }
    if (active) out[(size_t)wid * 40 + lane] = acc / zs + b2[lane];
}

// ---------------- host launch ----------------

extern "C" void kernel_launch(void* const* d_in, const int* in_sizes, int n_in,
                              void* d_out, int out_size, void* d_ws, size_t ws_size,
                              hipStream_t stream) {
    const float* x   = (const float*)d_in[0];
    const int*   ei  = (const int*)d_in[1];
    const float* W1  = (const float*)d_in[2];
    const float* a1s = (const float*)d_in[3];
    const float* a1d = (const float*)d_in[4];
    const float* b1  = (const float*)d_in[5];
    const float* W2  = (const float*)d_in[6];
    const float* a2s = (const float*)d_in[7];
    const float* a2d = (const float*)d_in[8];
    const float* b2  = (const float*)d_in[9];
    float* out = (float*)d_out;

    const int F = 128;
    const int N = in_sizes[0] / F;
    const int E = in_sizes[1] / 2;
    const int ET = E + N;

    char* ws = (char*)d_ws;
    size_t off = 0;
    auto alloc = [&](size_t bytes) -> char* {
        char* p = ws + off;
        off += (bytes + 255) & ~(size_t)255;
        return p;
    };
    u16*   h     = (u16*)alloc((size_t)N * 512 * 2);
    u16*   h2    = (u16*)alloc((size_t)N * 512 * 2);
    u16*   xb    = (u16*)alloc((size_t)N * 128 * 2);
    u16*   w1t   = (u16*)alloc((size_t)512 * 128 * 2);
    u16*   w2t   = (u16*)alloc((size_t)64 * 512 * 2);
    int*   esrc  = (int*)alloc((size_t)ET * 4);
    float* als1  = (float*)alloc((size_t)N * 8 * 4);
    float* ald1  = (float*)alloc((size_t)N * 8 * 4);
    int*   deg   = (int*)alloc((size_t)N * 4);
    int*   offs  = (int*)alloc((size_t)(N + 1) * 4);
    int*   curs  = (int*)alloc((size_t)N * 4);

    // layer-2 buffers alias the h region (h is dead after agg1_fused)
    char* l2 = (char*)h;
    size_t o2 = 0;
    auto alloc2 = [&](size_t bytes) -> char* {
        char* p = l2 + o2;
        o2 += (bytes + 255) & ~(size_t)255;
        return p;
    };
    float* g    = (float*)alloc2((size_t)N * 40 * 4);
    float* als2 = (float*)alloc2((size_t)N * 4);
    float* ald2 = (float*)alloc2((size_t)N * 4);

    const int TPB = 256;
    const int* e_src = ei;
    const int* e_dst = ei + E;

    // CSR build + input prep
    init_deg_kernel<<<(N + TPB - 1) / TPB, TPB, 0, stream>>>(deg, N);
    hist_kernel<<<(E + TPB - 1) / TPB, TPB, 0, stream>>>(e_dst, deg, E);
    scan_kernel<<<1, 1024, 0, stream>>>(deg, offs, curs, N);
    scatter_kernel<<<(ET + TPB - 1) / TPB, TPB, 0, stream>>>(e_src, e_dst, curs, esrc, E, N);
    cast_bf16_kernel<<<(N * 128 / 4 + TPB - 1) / TPB, TPB, 0, stream>>>(x, xb, N * 128);
    prep_w1t_kernel<<<512 * 128 / TPB, TPB, 0, stream>>>(W1, w1t);
    prep_w2t_kernel<<<64 * 512 / TPB, TPB, 0, stream>>>(W2, w2t);

    // layer 1
    mfma_gemm<128, true><<<dim3((N + 127) / 128, 4), 256, 0, stream>>>(
        xb, w1t, h, N, 128, 512, 512);
    logits1_kernel<<<(N * 8 + TPB - 1) / TPB, TPB, 0, stream>>>(h, a1s, a1d, als1, ald1, N);
    agg1_fused<<<(N + 3) / 4, 256, 0, stream>>>(offs, esrc, h, als1, ald1, b1, h2, N);

    // layer 2
    mfma_gemm<64, false><<<dim3((N + 127) / 128, 1), 256, 0, stream>>>(
        h2, w2t, g, N, 512, 40, 40);
    logits2_kernel<<<(N + TPB - 1) / TPB, TPB, 0, stream>>>(g, a2s, a2d, als2, ald2, N);
    agg2_fused<<<(N + 3) / 4, 256, 0, stream>>>(offs, esrc, g, als2, ald2, b2, out, N);
}